// Round 7
// baseline (231.335 us; speedup 1.0000x reference)
//
#include <hip/hip_runtime.h>
#include <stdint.h>

typedef __attribute__((ext_vector_type(4))) float f32x4;
typedef __attribute__((ext_vector_type(8))) short bf16x8;
typedef __attribute__((ext_vector_type(4))) unsigned short u16x4;
typedef __attribute__((ext_vector_type(4))) unsigned int u32x4;

typedef __attribute__((address_space(3))) char lds_t;
typedef const __attribute__((address_space(1))) char gmem_t;

__device__ __forceinline__ float bf2f(unsigned short u) {
  union { unsigned int u; float f; } a; a.u = ((unsigned int)u) << 16; return a.f;
}
__device__ __forceinline__ unsigned short f2bf(float f) {
  union { float f; unsigned int u; } a; a.f = f;
  unsigned int r = a.u + 0x7fffu + ((a.u >> 16) & 1u);  // RNE (finite inputs)
  return (unsigned short)(r >> 16);
}

// ---------------- fp32 -> bf16 convert, all tensors in ONE dispatch ----------------
// blocks [0,8192): x (16M elems); [8192,+512) Wq; +512 Wk; +512 Wv; +512 Wo.
__global__ __launch_bounds__(256) void cvt_all(
    const float* __restrict__ x, const float* __restrict__ W0, const float* __restrict__ W1,
    const float* __restrict__ W2, const float* __restrict__ W3,
    unsigned short* __restrict__ xb, unsigned short* __restrict__ wqkv,
    unsigned short* __restrict__ wob)
{
  const int b = blockIdx.x;
  const float* src;
  unsigned short* dst;
  int i;
  if (b < 8192) {
    src = x; dst = xb; i = b * 2048 + threadIdx.x * 8;
  } else {
    const int s = (b - 8192) >> 9;
    const int bb = (b - 8192) & 511;
    i = bb * 2048 + threadIdx.x * 8;
    src = (s == 0) ? W0 : (s == 1) ? W1 : (s == 2) ? W2 : W3;
    dst = (s < 3) ? (wqkv + s * 1048576) : wob;
  }
  const f32x4 a = *(const f32x4*)(src + i);
  const f32x4 c = *(const f32x4*)(src + i + 4);
  alignas(16) unsigned short o[8];
#pragma unroll
  for (int k = 0; k < 4; ++k) { o[k] = f2bf(a[k]); o[4 + k] = f2bf(c[k]); }
  *(u32x4*)(dst + i) = *(const u32x4*)o;
}

// ---------------- bf16 GEMM  C = A @ B^T — 256^2 8-phase template (m201/m204) ----------------
// Main loop unchanged (verified schedule). Epilogues LDS-bounced:
// MODE 0: fp32 out ([128][264] fp32 bounce per half, coalesced f32x4 stores).
// MODE 1: q l2norm -> normal layout; k l2norm / v sigmoid-scale -> TRANSPOSED per (n,h)
//         [64][1024]; all via [256][280] bf16 bounce with coalesced 16B stores.
template<int GX, int MODE>
__global__ __launch_bounds__(512, 2) void gemm256(
    const unsigned short* __restrict__ A, const unsigned short* __restrict__ B,
    void* __restrict__ O0, void* __restrict__ O1, void* __restrict__ O2,
    const float* __restrict__ nc)
{
  constexpr int K = 1024;
  constexpr int NT = K / 64;
  constexpr int NWG = GX * 64;
  constexpr int CPX = NWG >> 3;
  const int p = blockIdx.y * GX + blockIdx.x;
  const int lid = (p & 7) * CPX + (p >> 3);        // bijective (NWG % 8 == 0)
  const int bm0 = (lid / GX) * 256;
  const int bn0 = (lid % GX) * 256;
  const int t = threadIdx.x;
  const int l = t & 63;
  const int w = t >> 6;
  const int wm = w >> 2;
  const int wn = w & 3;

  __shared__ char smem[143360];   // main loop uses [0,131072); epilogue bounce up to 143360

  const int srow = t >> 3;
  const int schunk = t & 7;
  const int sck = schunk ^ (srow & 7);

#define STAGE_A(so_, kt_, lam_)                                                                  \
  __builtin_amdgcn_global_load_lds(                                                             \
      (gmem_t*)(A + (long long)(bm0 + (lam_) * 64 + srow) * K + (kt_) * 64 + sck * 8),          \
      (lds_t*)(smem + (so_) + ((lam_) * 64 + srow) * 128 + schunk * 16), 16, 0, 0)
#define STAGE_B(so_, kt_, lam_)                                                                  \
  __builtin_amdgcn_global_load_lds(                                                             \
      (gmem_t*)(B + (long long)(bn0 + (lam_) * 64 + srow) * K + (kt_) * 64 + sck * 8),          \
      (lds_t*)(smem + (so_) + 32768 + ((lam_) * 64 + srow) * 128 + schunk * 16), 16, 0, 0)

  const int xr = l & 7;
  const int chalf = l >> 4;
  int aoff[8], boff[4];
#pragma unroll
  for (int fr = 0; fr < 8; ++fr) aoff[fr] = (wm * 128 + fr * 16 + (l & 15)) * 128;
#pragma unroll
  for (int fc = 0; fc < 4; ++fc) boff[fc] = 32768 + (wn * 64 + fc * 16 + (l & 15)) * 128;

  f32x4 acc[8][4];
#pragma unroll
  for (int i = 0; i < 8; ++i)
#pragma unroll
    for (int j = 0; j < 4; ++j) acc[i][j] = f32x4{0.f, 0.f, 0.f, 0.f};

#pragma unroll
  for (int lam = 0; lam < 4; ++lam) STAGE_A(0, 0, lam);
#pragma unroll
  for (int lam = 0; lam < 4; ++lam) STAGE_B(0, 0, lam);
#pragma unroll
  for (int lam = 0; lam < 4; ++lam) STAGE_B(65536, 1, lam);
  asm volatile("s_waitcnt vmcnt(4)" ::: "memory");
  __builtin_amdgcn_s_barrier();
  __builtin_amdgcn_sched_barrier(0);

  for (int u = 0; u < NT; ++u) {
    const int slot = (u & 1) << 16;
    const int nslot = slot ^ 65536;
    bf16x8 bv[4][2];
#pragma unroll
    for (int q = 0; q < 4; ++q) {
      if (q == 0) {
#pragma unroll
        for (int j = 0; j < 4; ++j)
#pragma unroll
          for (int ks = 0; ks < 2; ++ks)
            bv[j][ks] = *(const bf16x8*)(smem + slot + boff[j] + (((ks * 4 + chalf) ^ xr) * 16));
      }
      bf16x8 av[2][2];
#pragma unroll
      for (int d = 0; d < 2; ++d)
#pragma unroll
        for (int ks = 0; ks < 2; ++ks)
          av[d][ks] = *(const bf16x8*)(smem + slot + aoff[2 * q + d] + (((ks * 4 + chalf) ^ xr) * 16));
      if (q == 0)      { if (u + 1 < NT) { STAGE_A(nslot, u + 1, 0); STAGE_A(nslot, u + 1, 1); } }
      else if (q == 1) { if (u + 1 < NT) { STAGE_A(nslot, u + 1, 2); STAGE_A(nslot, u + 1, 3); } }
      else if (q == 2) { if (u + 2 < NT) { STAGE_B(slot, u + 2, 0);  STAGE_B(slot, u + 2, 1); } }
      else             { if (u + 2 < NT) { STAGE_B(slot, u + 2, 2);  STAGE_B(slot, u + 2, 3); } }
      __builtin_amdgcn_s_barrier();
      asm volatile("s_waitcnt lgkmcnt(0)" ::: "memory");
      __builtin_amdgcn_sched_barrier(0);
      __builtin_amdgcn_s_setprio(1);
#pragma unroll
      for (int d = 0; d < 2; ++d)
#pragma unroll
        for (int j = 0; j < 4; ++j)
#pragma unroll
          for (int ks = 0; ks < 2; ++ks)
            acc[2 * q + d][j] =
                __builtin_amdgcn_mfma_f32_16x16x32_bf16(av[d][ks], bv[j][ks], acc[2 * q + d][j], 0, 0, 0);
      __builtin_amdgcn_s_setprio(0);
      if (q == 3) {
        if (u + 2 < NT) { asm volatile("s_waitcnt vmcnt(4)" ::: "memory"); }
        else            { asm volatile("s_waitcnt vmcnt(0)" ::: "memory"); }
      }
      __builtin_amdgcn_s_barrier();
      __builtin_amdgcn_sched_barrier(0);
    }
  }
#undef STAGE_A
#undef STAGE_B

  // ---- epilogue (LDS-bounce; main-loop LDS is dead) ----
  const int wcol0 = bn0 + wn * 64;
  const int rowb_l = wm * 128 + (l >> 4) * 4;    // local row base
  const int colb_l = wn * 64 + (l & 15);         // local col base

  if (MODE == 0) {
    float* ldsf = (float*)smem;                  // [128][264] fp32 per half (264*128*4 = 135168 B)
#pragma unroll
    for (int hi = 0; hi < 2; ++hi) {
      if (wm == hi) {
#pragma unroll
        for (int i = 0; i < 8; ++i)
#pragma unroll
          for (int j = 0; j < 4; ++j)
#pragma unroll
            for (int r = 0; r < 4; ++r)
              ldsf[((l >> 4) * 4 + i * 16 + r) * 264 + colb_l + j * 16] = acc[i][j][r];
      }
      __syncthreads();
      {
        const int row = t & 127, cq = t >> 7;
        float* dst = (float*)O0 + (long long)(bm0 + hi * 128 + row) * 1024 + bn0 + cq * 64;
        const float* srcl = ldsf + row * 264 + cq * 64;
#pragma unroll
        for (int g = 0; g < 16; ++g)
          *(f32x4*)(dst + g * 4) = *(const f32x4*)(srcl + g * 4);
      }
      __syncthreads();
    }
  } else {
    const int sel = wcol0 >> 10;                 // 0:q 1:k 2:v
    const int col_in = wcol0 & 1023;
    const int h = col_in >> 6;
    if (sel < 2) {
#pragma unroll
      for (int i = 0; i < 8; ++i)
#pragma unroll
        for (int r = 0; r < 4; ++r) {
          float s = 0.f;
#pragma unroll
          for (int j = 0; j < 4; ++j) s += acc[i][j][r] * acc[i][j][r];
          s += __shfl_xor(s, 1); s += __shfl_xor(s, 2);
          s += __shfl_xor(s, 4); s += __shfl_xor(s, 8);
          const float inv = 1.f / fmaxf(sqrtf(s), 1e-12f);
#pragma unroll
          for (int j = 0; j < 4; ++j) acc[i][j][r] *= inv;
        }
    } else {
      const float sig = 1.f / (1.f + expf(-nc[h]));
      const float vsc = expf(-6.9314718055994530942f * sig);  // 1024^-sig
#pragma unroll
      for (int i = 0; i < 8; ++i)
#pragma unroll
        for (int j = 0; j < 4; ++j)
#pragma unroll
          for (int r = 0; r < 4; ++r) acc[i][j][r] *= vsc;
    }
    unsigned short* lds16 = (unsigned short*)smem;  // [256][280] bf16 (143360 B)
    if (sel == 0) {
#pragma unroll
      for (int i = 0; i < 8; ++i)
#pragma unroll
        for (int j = 0; j < 4; ++j)
#pragma unroll
          for (int r = 0; r < 4; ++r)
            lds16[(rowb_l + i * 16 + r) * 280 + colb_l + j * 16] = f2bf(acc[i][j][r]);
      __syncthreads();
      const int row = t & 255, half = t >> 8;
      unsigned short* dst = (unsigned short*)O0 + (long long)(bm0 + row) * 1024 + bn0 + half * 128;
      const unsigned short* srcl = lds16 + row * 280 + half * 128;
#pragma unroll
      for (int g = 0; g < 16; ++g)
        *(u32x4*)(dst + g * 8) = *(const u32x4*)(srcl + g * 8);
    } else {
      // transposed into lds16[T-row d(=local col)][c(=local row)]
#pragma unroll
      for (int i = 0; i < 8; ++i)
#pragma unroll
        for (int j = 0; j < 4; ++j)
#pragma unroll
          for (int r = 0; r < 4; ++r)
            lds16[(colb_l + j * 16) * 280 + rowb_l + i * 16 + r] = f2bf(acc[i][j][r]);
      __syncthreads();
      const int d = t & 255, chalf = t >> 8;
      const int hh = ((bn0 & 1023) + d) >> 6;
      const int dg = ((bn0 & 1023) + d) & 63;
      const int n = bm0 >> 10;
      unsigned short* Tp = (unsigned short*)(sel == 1 ? O1 : O2);
      unsigned short* dst = Tp + ((long long)((n * 16 + hh) * 64 + dg)) * 1024
                          + (bm0 & 1023) + chalf * 128;
      const unsigned short* srcl = lds16 + d * 280 + chalf * 128;
#pragma unroll
      for (int g = 0; g < 16; ++g)
        *(u32x4*)(dst + g * 8) = *(const u32x4*)(srcl + g * 8);
    }
  }
}

// ---------------- kvT[e][d] = sum_c vT[e][c]*kT[d][c] per (n,h), MFMA split-K ----------------
__global__ __launch_bounds__(256) void kv_mfma(
    const unsigned short* __restrict__ vT, const unsigned short* __restrict__ kT,
    unsigned short* __restrict__ kvT)
{
  const int h = blockIdx.x, n = blockIdx.y;
  const int t = threadIdx.x, l = t & 63, w = t >> 6;
  __shared__ char smem[131072];
  const long long base = (long long)(n * 16 + h) * 64 * 1024;
  const int srow = l >> 3;
  const int schunk = l & 7;
  char* wbuf = smem + w * 32768;

#define KV_STAGE(buf_, cc_) do {                                                                  \
    const int col_ = w * 256 + (cc_) * 64;                                                        \
    _Pragma("unroll")                                                                             \
    for (int i_ = 0; i_ < 8; ++i_) {                                                              \
      const int r_ = i_ * 8 + srow;                                                               \
      const int sc_ = schunk ^ srow;                                                              \
      __builtin_amdgcn_global_load_lds((gmem_t*)(vT + base + (long long)r_ * 1024 + col_ + sc_ * 8), \
                                       (lds_t*)((buf_) + r_ * 128 + schunk * 16), 16, 0, 0);      \
      __builtin_amdgcn_global_load_lds((gmem_t*)(kT + base + (long long)r_ * 1024 + col_ + sc_ * 8), \
                                       (lds_t*)((buf_) + 8192 + r_ * 128 + schunk * 16), 16, 0, 0); \
    }                                                                                             \
  } while (0)

  const int xr = l & 7, chalf = l >> 4;
  f32x4 acc[4][4];
#pragma unroll
  for (int i = 0; i < 4; ++i)
#pragma unroll
    for (int j = 0; j < 4; ++j) acc[i][j] = f32x4{0.f, 0.f, 0.f, 0.f};

  KV_STAGE(wbuf, 0);
  for (int cc = 0; cc < 4; ++cc) {
    char* cur = wbuf + (cc & 1) * 16384;
    if (cc < 3) {
      KV_STAGE(wbuf + ((cc + 1) & 1) * 16384, cc + 1);
      asm volatile("s_waitcnt vmcnt(16)" ::: "memory");
    } else {
      asm volatile("s_waitcnt vmcnt(0)" ::: "memory");
    }
    bf16x8 av[4][2], bvv[4][2];
#pragma unroll
    for (int m = 0; m < 4; ++m)
#pragma unroll
      for (int ks = 0; ks < 2; ++ks) {
        const int ch = ((ks * 4 + chalf) ^ xr) * 16;
        av[m][ks]  = *(const bf16x8*)(cur + (m * 16 + (l & 15)) * 128 + ch);
        bvv[m][ks] = *(const bf16x8*)(cur + 8192 + (m * 16 + (l & 15)) * 128 + ch);
      }
#pragma unroll
    for (int m = 0; m < 4; ++m)
#pragma unroll
      for (int j = 0; j < 4; ++j)
#pragma unroll
        for (int ks = 0; ks < 2; ++ks)
          acc[m][j] = __builtin_amdgcn_mfma_f32_16x16x32_bf16(av[m][ks], bvv[j][ks], acc[m][j], 0, 0, 0);
  }
#undef KV_STAGE

  __syncthreads();
  float* red = (float*)smem;                        // [4 waves][16 frags][256]
#pragma unroll
  for (int m = 0; m < 4; ++m)
#pragma unroll
    for (int j = 0; j < 4; ++j)
      *(f32x4*)&red[w * 4096 + (m * 4 + j) * 256 + l * 4] = acc[m][j];
  __syncthreads();

  const int e = t >> 2, d0 = (t & 3) * 16;
  const int m = e >> 4, rr = e & 3, lhi = (e & 15) >> 2;
  alignas(16) unsigned short o16[16];
#pragma unroll
  for (int dd = 0; dd < 16; ++dd) {
    const int d = d0 + dd;
    const int f = m * 4 + (d >> 4);
    const int pos = (lhi * 16 + (d & 15)) * 4 + rr;
    float s = red[f * 256 + pos] + red[4096 + f * 256 + pos] +
              red[8192 + f * 256 + pos] + red[12288 + f * 256 + pos];
    o16[dd] = f2bf(s);
  }
  unsigned short* dst = kvT + (long long)(n * 16 + h) * 4096 + e * 64 + d0;
  *(u32x4*)dst = *(const u32x4*)&o16[0];
  *((u32x4*)dst + 1) = *(const u32x4*)&o16[8];
}

// ---------------- attn[c][h*64+e] = sum_d q[c][h*64+d]*kvT[e][d]; in-place over q ----------------
__global__ __launch_bounds__(256) void attn_mfma(
    unsigned short* __restrict__ q, const unsigned short* __restrict__ kvT)
{
  const int ct = blockIdx.x, h = blockIdx.y, n = blockIdx.z;
  const int t = threadIdx.x, l = t & 63, w = t >> 6;
  __shared__ char smem[40960];                     // q tile 32KB + kvT 8KB
  const long long R0 = (long long)n * 1024 + ct * 256;
  {
    const int sr = t >> 3;
    const int sc = (t & 7) ^ (sr & 7);
#pragma unroll
    for (int i = 0; i < 8; ++i) {
      const int r = i * 32 + sr;
      __builtin_amdgcn_global_load_lds((gmem_t*)(q + (R0 + r) * 1024 + h * 64 + sc * 8),
                                       (lds_t*)(smem + r * 128 + (t & 7) * 16), 16, 0, 0);
    }
#pragma unroll
    for (int i = 0; i < 2; ++i) {
      const int r = i * 32 + sr;
      __builtin_amdgcn_global_load_lds((gmem_t*)(kvT + (long long)(n * 16 + h) * 4096 + r * 64 + sc * 8),
                                       (lds_t*)(smem + 32768 + r * 128 + (t & 7) * 16), 16, 0, 0);
    }
  }
  asm volatile("s_waitcnt vmcnt(0)" ::: "memory");
  __syncthreads();

  const int xr = l & 7, chalf = l >> 4;
  f32x4 acc[4][4];
#pragma unroll
  for (int i = 0; i < 4; ++i)
#pragma unroll
    for (int j = 0; j < 4; ++j) acc[i][j] = f32x4{0.f, 0.f, 0.f, 0.f};
  bf16x8 av[4][2], bvv[4][2];
#pragma unroll
  for (int m = 0; m < 4; ++m)
#pragma unroll
    for (int ks = 0; ks < 2; ++ks) {
      const int ch = ((ks * 4 + chalf) ^ xr) * 16;
      av[m][ks]  = *(const bf16x8*)(smem + (w * 64 + m * 16 + (l & 15)) * 128 + ch);
      bvv[m][ks] = *(const bf16x8*)(smem + 32768 + (m * 16 + (l & 15)) * 128 + ch);
    }
#pragma unroll
  for (int m = 0; m < 4; ++m)
#pragma unroll
    for (int j = 0; j < 4; ++j)
#pragma unroll
      for (int ks = 0; ks < 2; ++ks)
        acc[m][j] = __builtin_amdgcn_mfma_f32_16x16x32_bf16(av[m][ks], bvv[j][ks], acc[m][j], 0, 0, 0);

  const int rb = w * 64 + (l >> 4) * 4;
#pragma unroll
  for (int m = 0; m < 4; ++m)
#pragma unroll
    for (int j = 0; j < 4; ++j)
#pragma unroll
      for (int r = 0; r < 4; ++r)
        q[(R0 + rb + m * 16 + r) * 1024 + h * 64 + j * 16 + (l & 15)] = f2bf(acc[m][j][r]);
}

extern "C" void kernel_launch(void* const* d_in, const int* in_sizes, int n_in,
                              void* d_out, int out_size, void* d_ws, size_t ws_size,
                              hipStream_t stream) {
  (void)in_sizes; (void)n_in; (void)out_size; (void)ws_size;
  const float* x  = (const float*)d_in[0];
  const float* Wq = (const float*)d_in[1];
  const float* Wk = (const float*)d_in[2];
  const float* Wv = (const float*)d_in[3];
  const float* Wo = (const float*)d_in[4];
  const float* nc = (const float*)d_in[5];

  // d_out (64 MB fp32) scratch: xb [0,32MB) (dead after QKV), kvT at +32MB (dead before Wo write)
  unsigned short* xb  = (unsigned short*)d_out;
  unsigned short* kvT = (unsigned short*)((char*)d_out + 33554432ll);

  char* ws = (char*)d_ws;
  unsigned short* wqkv = (unsigned short*)ws;          // [3072][1024] = Wq;Wk;Wv
  unsigned short* wob  = wqkv + 3 * 1048576;
  unsigned short* qb   = wob + 1048576;                // q, then attn in place
  unsigned short* kTb  = qb + 16777216;                // k transposed [n][h][64][1024]
  unsigned short* vTb  = kTb + 16777216;               // v transposed [n][h][64][1024]

  cvt_all<<<10240, 256, 0, stream>>>(x, Wq, Wk, Wv, Wo, xb, wqkv, wob);

  gemm256<12, 1><<<dim3(12, 64), 512, 0, stream>>>(xb, wqkv, qb, kTb, vTb, nc);
  kv_mfma<<<dim3(16, 16), 256, 0, stream>>>(vTb, kTb, kvT);
  attn_mfma<<<dim3(4, 16, 16), 256, 0, stream>>>(qb, kvT);
  gemm256<4, 0><<<dim3(4, 64), 512, 0, stream>>>(qb, wob, d_out, nullptr, nullptr, nullptr);
}

// Round 8
// 214.383 us; speedup vs baseline: 1.0791x; 1.0791x over previous
//
#include <hip/hip_runtime.h>
#include <stdint.h>

typedef __attribute__((ext_vector_type(4))) float f32x4;
typedef __attribute__((ext_vector_type(8))) short bf16x8;
typedef __attribute__((ext_vector_type(4))) unsigned short u16x4;
typedef __attribute__((ext_vector_type(4))) unsigned int u32x4;

typedef __attribute__((address_space(3))) char lds_t;
typedef const __attribute__((address_space(1))) char gmem_t;

__device__ __forceinline__ float bf2f(unsigned short u) {
  union { unsigned int u; float f; } a; a.u = ((unsigned int)u) << 16; return a.f;
}
__device__ __forceinline__ unsigned short f2bf(float f) {
  union { float f; unsigned int u; } a; a.f = f;
  unsigned int r = a.u + 0x7fffu + ((a.u >> 16) & 1u);  // RNE (finite inputs)
  return (unsigned short)(r >> 16);
}

// ---------------- fp32 -> bf16 convert, all tensors in ONE dispatch ----------------
// blocks [0,8192): x (16M elems); [8192,+512) Wq; +512 Wk; +512 Wv; +512 Wo.
__global__ __launch_bounds__(256) void cvt_all(
    const float* __restrict__ x, const float* __restrict__ W0, const float* __restrict__ W1,
    const float* __restrict__ W2, const float* __restrict__ W3,
    unsigned short* __restrict__ xb, unsigned short* __restrict__ wqkv,
    unsigned short* __restrict__ wob)
{
  const int b = blockIdx.x;
  const float* src;
  unsigned short* dst;
  int i;
  if (b < 8192) {
    src = x; dst = xb; i = b * 2048 + threadIdx.x * 8;
  } else {
    const int s = (b - 8192) >> 9;
    const int bb = (b - 8192) & 511;
    i = bb * 2048 + threadIdx.x * 8;
    src = (s == 0) ? W0 : (s == 1) ? W1 : (s == 2) ? W2 : W3;
    dst = (s < 3) ? (wqkv + s * 1048576) : wob;
  }
  const f32x4 a = *(const f32x4*)(src + i);
  const f32x4 c = *(const f32x4*)(src + i + 4);
  alignas(16) unsigned short o[8];
#pragma unroll
  for (int k = 0; k < 4; ++k) { o[k] = f2bf(a[k]); o[4 + k] = f2bf(c[k]); }
  *(u32x4*)(dst + i) = *(const u32x4*)o;
}

// ---------------- bf16 GEMM  C = A @ B^T — 256^2 8-phase template (m201/m204) ----------------
// Main loop: verified schedule (unchanged since R4). Direct-store epilogues (R5 style);
// transposed kT/vT stores vectorized as u16x4 (4 consecutive c per thread).
// MODE 0: fp32 out. MODE 1: q l2norm -> normal layout; k l2norm / v sigmoid-scale ->
// TRANSPOSED per (n,h) as [64][1024].
template<int GX, int MODE>
__global__ __launch_bounds__(512, 2) void gemm256(
    const unsigned short* __restrict__ A, const unsigned short* __restrict__ B,
    void* __restrict__ O0, void* __restrict__ O1, void* __restrict__ O2,
    const float* __restrict__ nc)
{
  constexpr int K = 1024;
  constexpr int NT = K / 64;
  constexpr int NWG = GX * 64;
  constexpr int CPX = NWG >> 3;
  const int p = blockIdx.y * GX + blockIdx.x;
  const int lid = (p & 7) * CPX + (p >> 3);        // bijective (NWG % 8 == 0)
  const int bm0 = (lid / GX) * 256;
  const int bn0 = (lid % GX) * 256;
  const int t = threadIdx.x;
  const int l = t & 63;
  const int w = t >> 6;
  const int wm = w >> 2;
  const int wn = w & 3;

  __shared__ char smem[131072];

  const int srow = t >> 3;
  const int schunk = t & 7;
  const int sck = schunk ^ (srow & 7);

#define STAGE_A(so_, kt_, lam_)                                                                  \
  __builtin_amdgcn_global_load_lds(                                                             \
      (gmem_t*)(A + (long long)(bm0 + (lam_) * 64 + srow) * K + (kt_) * 64 + sck * 8),          \
      (lds_t*)(smem + (so_) + ((lam_) * 64 + srow) * 128 + schunk * 16), 16, 0, 0)
#define STAGE_B(so_, kt_, lam_)                                                                  \
  __builtin_amdgcn_global_load_lds(                                                             \
      (gmem_t*)(B + (long long)(bn0 + (lam_) * 64 + srow) * K + (kt_) * 64 + sck * 8),          \
      (lds_t*)(smem + (so_) + 32768 + ((lam_) * 64 + srow) * 128 + schunk * 16), 16, 0, 0)

  const int xr = l & 7;
  const int chalf = l >> 4;
  int aoff[8], boff[4];
#pragma unroll
  for (int fr = 0; fr < 8; ++fr) aoff[fr] = (wm * 128 + fr * 16 + (l & 15)) * 128;
#pragma unroll
  for (int fc = 0; fc < 4; ++fc) boff[fc] = 32768 + (wn * 64 + fc * 16 + (l & 15)) * 128;

  f32x4 acc[8][4];
#pragma unroll
  for (int i = 0; i < 8; ++i)
#pragma unroll
    for (int j = 0; j < 4; ++j) acc[i][j] = f32x4{0.f, 0.f, 0.f, 0.f};

#pragma unroll
  for (int lam = 0; lam < 4; ++lam) STAGE_A(0, 0, lam);
#pragma unroll
  for (int lam = 0; lam < 4; ++lam) STAGE_B(0, 0, lam);
#pragma unroll
  for (int lam = 0; lam < 4; ++lam) STAGE_B(65536, 1, lam);
  asm volatile("s_waitcnt vmcnt(4)" ::: "memory");
  __builtin_amdgcn_s_barrier();
  __builtin_amdgcn_sched_barrier(0);

  for (int u = 0; u < NT; ++u) {
    const int slot = (u & 1) << 16;
    const int nslot = slot ^ 65536;
    bf16x8 bv[4][2];
#pragma unroll
    for (int q = 0; q < 4; ++q) {
      if (q == 0) {
#pragma unroll
        for (int j = 0; j < 4; ++j)
#pragma unroll
          for (int ks = 0; ks < 2; ++ks)
            bv[j][ks] = *(const bf16x8*)(smem + slot + boff[j] + (((ks * 4 + chalf) ^ xr) * 16));
      }
      bf16x8 av[2][2];
#pragma unroll
      for (int d = 0; d < 2; ++d)
#pragma unroll
        for (int ks = 0; ks < 2; ++ks)
          av[d][ks] = *(const bf16x8*)(smem + slot + aoff[2 * q + d] + (((ks * 4 + chalf) ^ xr) * 16));
      if (q == 0)      { if (u + 1 < NT) { STAGE_A(nslot, u + 1, 0); STAGE_A(nslot, u + 1, 1); } }
      else if (q == 1) { if (u + 1 < NT) { STAGE_A(nslot, u + 1, 2); STAGE_A(nslot, u + 1, 3); } }
      else if (q == 2) { if (u + 2 < NT) { STAGE_B(slot, u + 2, 0);  STAGE_B(slot, u + 2, 1); } }
      else             { if (u + 2 < NT) { STAGE_B(slot, u + 2, 2);  STAGE_B(slot, u + 2, 3); } }
      __builtin_amdgcn_s_barrier();
      asm volatile("s_waitcnt lgkmcnt(0)" ::: "memory");
      __builtin_amdgcn_sched_barrier(0);
      __builtin_amdgcn_s_setprio(1);
#pragma unroll
      for (int d = 0; d < 2; ++d)
#pragma unroll
        for (int j = 0; j < 4; ++j)
#pragma unroll
          for (int ks = 0; ks < 2; ++ks)
            acc[2 * q + d][j] =
                __builtin_amdgcn_mfma_f32_16x16x32_bf16(av[d][ks], bv[j][ks], acc[2 * q + d][j], 0, 0, 0);
      __builtin_amdgcn_s_setprio(0);
      if (q == 3) {
        if (u + 2 < NT) { asm volatile("s_waitcnt vmcnt(4)" ::: "memory"); }
        else            { asm volatile("s_waitcnt vmcnt(0)" ::: "memory"); }
      }
      __builtin_amdgcn_s_barrier();
      __builtin_amdgcn_sched_barrier(0);
    }
  }
#undef STAGE_A
#undef STAGE_B

  // ---- epilogue: C/D layout col = lane&15, row = (lane>>4)*4 + reg ----
  const int wcol0 = bn0 + wn * 64;
  const int rowb = bm0 + wm * 128 + (l >> 4) * 4;

  if (MODE == 0) {
    float* Op = (float*)O0;
    const int colb = wcol0 + (l & 15);
#pragma unroll
    for (int i = 0; i < 8; ++i)
#pragma unroll
      for (int j = 0; j < 4; ++j)
#pragma unroll
        for (int r = 0; r < 4; ++r)
          Op[(long long)(rowb + i * 16 + r) * 1024 + (colb + j * 16)] = acc[i][j][r];
  } else {
    const int sel = wcol0 >> 10;                   // 0:q 1:k 2:v
    const int col_in = wcol0 & 1023;
    const int h = col_in >> 6;
    if (sel < 2) {
#pragma unroll
      for (int i = 0; i < 8; ++i)
#pragma unroll
        for (int r = 0; r < 4; ++r) {
          float s = 0.f;
#pragma unroll
          for (int j = 0; j < 4; ++j) s += acc[i][j][r] * acc[i][j][r];
          s += __shfl_xor(s, 1); s += __shfl_xor(s, 2);
          s += __shfl_xor(s, 4); s += __shfl_xor(s, 8);
          const float inv = 1.f / fmaxf(sqrtf(s), 1e-12f);
#pragma unroll
          for (int j = 0; j < 4; ++j) acc[i][j][r] *= inv;
        }
    } else {
      const float sig = 1.f / (1.f + expf(-nc[h]));
      const float vsc = expf(-6.9314718055994530942f * sig);  // 1024^-sig
#pragma unroll
      for (int i = 0; i < 8; ++i)
#pragma unroll
        for (int j = 0; j < 4; ++j)
#pragma unroll
          for (int r = 0; r < 4; ++r) acc[i][j][r] *= vsc;
    }
    if (sel == 0) {
      unsigned short* Op = (unsigned short*)O0;
      const int colb = col_in + (l & 15);
#pragma unroll
      for (int i = 0; i < 8; ++i)
#pragma unroll
        for (int j = 0; j < 4; ++j)
#pragma unroll
          for (int r = 0; r < 4; ++r)
            Op[(long long)(rowb + i * 16 + r) * 1024 + (colb + j * 16)] = f2bf(acc[i][j][r]);
    } else {
      // transposed: T[(n*16+h)*64 + d][c], d = j*16+(l&15), c = c0 + i*16 + r
      // 4 consecutive c per (i,j) -> one u16x4 8B store (c0 is 4-aligned).
      unsigned short* Tp = (unsigned short*)(sel == 1 ? O1 : O2)
                         + ((long long)((bm0 >> 10) * 16 + h) * 64) * 1024;
      const int c0 = (bm0 & 1023) + wm * 128 + (l >> 4) * 4;
#pragma unroll
      for (int j = 0; j < 4; ++j) {
        const long long drow = (long long)(j * 16 + (l & 15)) * 1024;
#pragma unroll
        for (int i = 0; i < 8; ++i) {
          u16x4 o;
#pragma unroll
          for (int r = 0; r < 4; ++r) o[r] = f2bf(acc[i][j][r]);
          *(u16x4*)(Tp + drow + c0 + i * 16) = o;
        }
      }
    }
  }
}

// ---------------- kvT[e][d] = sum_c vT[e][c]*kT[d][c] per (n,h), MFMA split-K ----------------
__global__ __launch_bounds__(256) void kv_mfma(
    const unsigned short* __restrict__ vT, const unsigned short* __restrict__ kT,
    unsigned short* __restrict__ kvT)
{
  const int h = blockIdx.x, n = blockIdx.y;
  const int t = threadIdx.x, l = t & 63, w = t >> 6;
  __shared__ char smem[131072];
  const long long base = (long long)(n * 16 + h) * 64 * 1024;
  const int srow = l >> 3;
  const int schunk = l & 7;
  char* wbuf = smem + w * 32768;

#define KV_STAGE(buf_, cc_) do {                                                                  \
    const int col_ = w * 256 + (cc_) * 64;                                                        \
    _Pragma("unroll")                                                                             \
    for (int i_ = 0; i_ < 8; ++i_) {                                                              \
      const int r_ = i_ * 8 + srow;                                                               \
      const int sc_ = schunk ^ srow;                                                              \
      __builtin_amdgcn_global_load_lds((gmem_t*)(vT + base + (long long)r_ * 1024 + col_ + sc_ * 8), \
                                       (lds_t*)((buf_) + r_ * 128 + schunk * 16), 16, 0, 0);      \
      __builtin_amdgcn_global_load_lds((gmem_t*)(kT + base + (long long)r_ * 1024 + col_ + sc_ * 8), \
                                       (lds_t*)((buf_) + 8192 + r_ * 128 + schunk * 16), 16, 0, 0); \
    }                                                                                             \
  } while (0)

  const int xr = l & 7, chalf = l >> 4;
  f32x4 acc[4][4];
#pragma unroll
  for (int i = 0; i < 4; ++i)
#pragma unroll
    for (int j = 0; j < 4; ++j) acc[i][j] = f32x4{0.f, 0.f, 0.f, 0.f};

  KV_STAGE(wbuf, 0);
  for (int cc = 0; cc < 4; ++cc) {
    char* cur = wbuf + (cc & 1) * 16384;
    if (cc < 3) {
      KV_STAGE(wbuf + ((cc + 1) & 1) * 16384, cc + 1);
      asm volatile("s_waitcnt vmcnt(16)" ::: "memory");
    } else {
      asm volatile("s_waitcnt vmcnt(0)" ::: "memory");
    }
    bf16x8 av[4][2], bvv[4][2];
#pragma unroll
    for (int m = 0; m < 4; ++m)
#pragma unroll
      for (int ks = 0; ks < 2; ++ks) {
        const int ch = ((ks * 4 + chalf) ^ xr) * 16;
        av[m][ks]  = *(const bf16x8*)(cur + (m * 16 + (l & 15)) * 128 + ch);
        bvv[m][ks] = *(const bf16x8*)(cur + 8192 + (m * 16 + (l & 15)) * 128 + ch);
      }
#pragma unroll
    for (int m = 0; m < 4; ++m)
#pragma unroll
      for (int j = 0; j < 4; ++j)
#pragma unroll
        for (int ks = 0; ks < 2; ++ks)
          acc[m][j] = __builtin_amdgcn_mfma_f32_16x16x32_bf16(av[m][ks], bvv[j][ks], acc[m][j], 0, 0, 0);
  }
#undef KV_STAGE

  __syncthreads();
  float* red = (float*)smem;                        // [4 waves][16 frags][256]
#pragma unroll
  for (int m = 0; m < 4; ++m)
#pragma unroll
    for (int j = 0; j < 4; ++j)
      *(f32x4*)&red[w * 4096 + (m * 4 + j) * 256 + l * 4] = acc[m][j];
  __syncthreads();

  const int e = t >> 2, d0 = (t & 3) * 16;
  const int m = e >> 4, rr = e & 3, lhi = (e & 15) >> 2;
  alignas(16) unsigned short o16[16];
#pragma unroll
  for (int dd = 0; dd < 16; ++dd) {
    const int d = d0 + dd;
    const int f = m * 4 + (d >> 4);
    const int pos = (lhi * 16 + (d & 15)) * 4 + rr;
    float s = red[f * 256 + pos] + red[4096 + f * 256 + pos] +
              red[8192 + f * 256 + pos] + red[12288 + f * 256 + pos];
    o16[dd] = f2bf(s);
  }
  unsigned short* dst = kvT + (long long)(n * 16 + h) * 4096 + e * 64 + d0;
  *(u32x4*)dst = *(const u32x4*)&o16[0];
  *((u32x4*)dst + 1) = *(const u32x4*)&o16[8];
}

// ---------------- attn[c][h*64+e] = sum_d q[c][h*64+d]*kvT[e][d]; in-place over q ----------------
__global__ __launch_bounds__(256) void attn_mfma(
    unsigned short* __restrict__ q, const unsigned short* __restrict__ kvT)
{
  const int ct = blockIdx.x, h = blockIdx.y, n = blockIdx.z;
  const int t = threadIdx.x, l = t & 63, w = t >> 6;
  __shared__ char smem[40960];                     // q tile 32KB + kvT 8KB
  const long long R0 = (long long)n * 1024 + ct * 256;
  {
    const int sr = t >> 3;
    const int sc = (t & 7) ^ (sr & 7);
#pragma unroll
    for (int i = 0; i < 8; ++i) {
      const int r = i * 32 + sr;
      __builtin_amdgcn_global_load_lds((gmem_t*)(q + (R0 + r) * 1024 + h * 64 + sc * 8),
                                       (lds_t*)(smem + r * 128 + (t & 7) * 16), 16, 0, 0);
    }
#pragma unroll
    for (int i = 0; i < 2; ++i) {
      const int r = i * 32 + sr;
      __builtin_amdgcn_global_load_lds((gmem_t*)(kvT + (long long)(n * 16 + h) * 4096 + r * 64 + sc * 8),
                                       (lds_t*)(smem + 32768 + r * 128 + (t & 7) * 16), 16, 0, 0);
    }
  }
  asm volatile("s_waitcnt vmcnt(0)" ::: "memory");
  __syncthreads();

  const int xr = l & 7, chalf = l >> 4;
  f32x4 acc[4][4];
#pragma unroll
  for (int i = 0; i < 4; ++i)
#pragma unroll
    for (int j = 0; j < 4; ++j) acc[i][j] = f32x4{0.f, 0.f, 0.f, 0.f};
  bf16x8 av[4][2], bvv[4][2];
#pragma unroll
  for (int m = 0; m < 4; ++m)
#pragma unroll
    for (int ks = 0; ks < 2; ++ks) {
      const int ch = ((ks * 4 + chalf) ^ xr) * 16;
      av[m][ks]  = *(const bf16x8*)(smem + (w * 64 + m * 16 + (l & 15)) * 128 + ch);
      bvv[m][ks] = *(const bf16x8*)(smem + 32768 + (m * 16 + (l & 15)) * 128 + ch);
    }
#pragma unroll
  for (int m = 0; m < 4; ++m)
#pragma unroll
    for (int j = 0; j < 4; ++j)
#pragma unroll
      for (int ks = 0; ks < 2; ++ks)
        acc[m][j] = __builtin_amdgcn_mfma_f32_16x16x32_bf16(av[m][ks], bvv[j][ks], acc[m][j], 0, 0, 0);

  const int rb = w * 64 + (l >> 4) * 4;
#pragma unroll
  for (int m = 0; m < 4; ++m)
#pragma unroll
    for (int j = 0; j < 4; ++j)
#pragma unroll
      for (int r = 0; r < 4; ++r)
        q[(R0 + rb + m * 16 + r) * 1024 + h * 64 + j * 16 + (l & 15)] = f2bf(acc[m][j][r]);
}

extern "C" void kernel_launch(void* const* d_in, const int* in_sizes, int n_in,
                              void* d_out, int out_size, void* d_ws, size_t ws_size,
                              hipStream_t stream) {
  (void)in_sizes; (void)n_in; (void)out_size; (void)ws_size;
  const float* x  = (const float*)d_in[0];
  const float* Wq = (const float*)d_in[1];
  const float* Wk = (const float*)d_in[2];
  const float* Wv = (const float*)d_in[3];
  const float* Wo = (const float*)d_in[4];
  const float* nc = (const float*)d_in[5];

  // d_out (64 MB fp32) scratch: xb [0,32MB) (dead after QKV), kvT at +32MB (dead before Wo write)
  unsigned short* xb  = (unsigned short*)d_out;
  unsigned short* kvT = (unsigned short*)((char*)d_out + 33554432ll);

  char* ws = (char*)d_ws;
  unsigned short* wqkv = (unsigned short*)ws;          // [3072][1024] = Wq;Wk;Wv
  unsigned short* wob  = wqkv + 3 * 1048576;
  unsigned short* qb   = wob + 1048576;                // q, then attn in place
  unsigned short* kTb  = qb + 16777216;                // k transposed [n][h][64][1024]
  unsigned short* vTb  = kTb + 16777216;               // v transposed [n][h][64][1024]

  cvt_all<<<10240, 256, 0, stream>>>(x, Wq, Wk, Wv, Wo, xb, wqkv, wob);

  gemm256<12, 1><<<dim3(12, 64), 512, 0, stream>>>(xb, wqkv, qb, kTb, vTb, nc);
  kv_mfma<<<dim3(16, 16), 256, 0, stream>>>(vTb, kTb, kvT);
  attn_mfma<<<dim3(4, 16, 16), 256, 0, stream>>>(qb, kvT);
  gemm256<4, 0><<<dim3(4, 64), 512, 0, stream>>>(qb, wob, d_out, nullptr, nullptr, nullptr);
}

// Round 9
// 200.820 us; speedup vs baseline: 1.1520x; 1.0675x over previous
//
#include <hip/hip_runtime.h>
#include <stdint.h>

typedef __attribute__((ext_vector_type(4))) float f32x4;
typedef __attribute__((ext_vector_type(8))) short bf16x8;
typedef __attribute__((ext_vector_type(4))) unsigned short u16x4;
typedef __attribute__((ext_vector_type(4))) unsigned int u32x4;

typedef __attribute__((address_space(3))) char lds_t;
typedef const __attribute__((address_space(1))) char gmem_t;

__device__ __forceinline__ float bf2f(unsigned short u) {
  union { unsigned int u; float f; } a; a.u = ((unsigned int)u) << 16; return a.f;
}
__device__ __forceinline__ unsigned short f2bf(float f) {
  union { float f; unsigned int u; } a; a.f = f;
  unsigned int r = a.u + 0x7fffu + ((a.u >> 16) & 1u);  // RNE (finite inputs)
  return (unsigned short)(r >> 16);
}
__device__ __forceinline__ bf16x8 ld_pair512(const char* p) {
  union { bf16x8 v; u16x4 h[2]; } u;
  u.h[0] = *(const u16x4*)p;
  u.h[1] = *(const u16x4*)(p + 512);
  return u.v;
}

// ---------------- fp32 -> bf16 convert, all tensors in ONE dispatch ----------------
__global__ __launch_bounds__(256) void cvt_all(
    const float* __restrict__ x, const float* __restrict__ W0, const float* __restrict__ W1,
    const float* __restrict__ W2, const float* __restrict__ W3,
    unsigned short* __restrict__ xb, unsigned short* __restrict__ wqkv,
    unsigned short* __restrict__ wob)
{
  const int b = blockIdx.x;
  const float* src;
  unsigned short* dst;
  int i;
  if (b < 8192) {
    src = x; dst = xb; i = b * 2048 + threadIdx.x * 8;
  } else {
    const int s = (b - 8192) >> 9;
    const int bb = (b - 8192) & 511;
    i = bb * 2048 + threadIdx.x * 8;
    src = (s == 0) ? W0 : (s == 1) ? W1 : (s == 2) ? W2 : W3;
    dst = (s < 3) ? (wqkv + s * 1048576) : wob;
  }
  const f32x4 a = *(const f32x4*)(src + i);
  const f32x4 c = *(const f32x4*)(src + i + 4);
  alignas(16) unsigned short o[8];
#pragma unroll
  for (int k = 0; k < 4; ++k) { o[k] = f2bf(a[k]); o[4 + k] = f2bf(c[k]); }
  *(u32x4*)(dst + i) = *(const u32x4*)o;
}

// ---------------- bf16 GEMM  C = A @ B^T — 256^2 8-phase template (m201/m204) ----------------
// Main loop: verified schedule (unchanged since R4). MODE 0: fp32 out, direct stores.
// MODE 1: q l2norm -> normal layout (scalar stores); k l2norm / v sigmoid-scale ->
// chunk-interleaved layout L per (n,h): elem(d,c) at (c>>2)*256 + d*4 + (c&3).
// L-store: u16x4 per (i,j), 4x128B contiguous segments per store instruction.
template<int GX, int MODE>
__global__ __launch_bounds__(512, 2) void gemm256(
    const unsigned short* __restrict__ A, const unsigned short* __restrict__ B,
    void* __restrict__ O0, void* __restrict__ O1, void* __restrict__ O2,
    const float* __restrict__ nc)
{
  constexpr int K = 1024;
  constexpr int NT = K / 64;
  constexpr int NWG = GX * 64;
  constexpr int CPX = NWG >> 3;
  const int p = blockIdx.y * GX + blockIdx.x;
  const int lid = (p & 7) * CPX + (p >> 3);        // bijective (NWG % 8 == 0)
  const int bm0 = (lid / GX) * 256;
  const int bn0 = (lid % GX) * 256;
  const int t = threadIdx.x;
  const int l = t & 63;
  const int w = t >> 6;
  const int wm = w >> 2;
  const int wn = w & 3;

  __shared__ char smem[131072];

  const int srow = t >> 3;
  const int schunk = t & 7;
  const int sck = schunk ^ (srow & 7);

#define STAGE_A(so_, kt_, lam_)                                                                  \
  __builtin_amdgcn_global_load_lds(                                                             \
      (gmem_t*)(A + (long long)(bm0 + (lam_) * 64 + srow) * K + (kt_) * 64 + sck * 8),          \
      (lds_t*)(smem + (so_) + ((lam_) * 64 + srow) * 128 + schunk * 16), 16, 0, 0)
#define STAGE_B(so_, kt_, lam_)                                                                  \
  __builtin_amdgcn_global_load_lds(                                                             \
      (gmem_t*)(B + (long long)(bn0 + (lam_) * 64 + srow) * K + (kt_) * 64 + sck * 8),          \
      (lds_t*)(smem + (so_) + 32768 + ((lam_) * 64 + srow) * 128 + schunk * 16), 16, 0, 0)

  const int xr = l & 7;
  const int chalf = l >> 4;
  int aoff[8], boff[4];
#pragma unroll
  for (int fr = 0; fr < 8; ++fr) aoff[fr] = (wm * 128 + fr * 16 + (l & 15)) * 128;
#pragma unroll
  for (int fc = 0; fc < 4; ++fc) boff[fc] = 32768 + (wn * 64 + fc * 16 + (l & 15)) * 128;

  f32x4 acc[8][4];
#pragma unroll
  for (int i = 0; i < 8; ++i)
#pragma unroll
    for (int j = 0; j < 4; ++j) acc[i][j] = f32x4{0.f, 0.f, 0.f, 0.f};

#pragma unroll
  for (int lam = 0; lam < 4; ++lam) STAGE_A(0, 0, lam);
#pragma unroll
  for (int lam = 0; lam < 4; ++lam) STAGE_B(0, 0, lam);
#pragma unroll
  for (int lam = 0; lam < 4; ++lam) STAGE_B(65536, 1, lam);
  asm volatile("s_waitcnt vmcnt(4)" ::: "memory");
  __builtin_amdgcn_s_barrier();
  __builtin_amdgcn_sched_barrier(0);

  for (int u = 0; u < NT; ++u) {
    const int slot = (u & 1) << 16;
    const int nslot = slot ^ 65536;
    bf16x8 bv[4][2];
#pragma unroll
    for (int q = 0; q < 4; ++q) {
      if (q == 0) {
#pragma unroll
        for (int j = 0; j < 4; ++j)
#pragma unroll
          for (int ks = 0; ks < 2; ++ks)
            bv[j][ks] = *(const bf16x8*)(smem + slot + boff[j] + (((ks * 4 + chalf) ^ xr) * 16));
      }
      bf16x8 av[2][2];
#pragma unroll
      for (int d = 0; d < 2; ++d)
#pragma unroll
        for (int ks = 0; ks < 2; ++ks)
          av[d][ks] = *(const bf16x8*)(smem + slot + aoff[2 * q + d] + (((ks * 4 + chalf) ^ xr) * 16));
      if (q == 0)      { if (u + 1 < NT) { STAGE_A(nslot, u + 1, 0); STAGE_A(nslot, u + 1, 1); } }
      else if (q == 1) { if (u + 1 < NT) { STAGE_A(nslot, u + 1, 2); STAGE_A(nslot, u + 1, 3); } }
      else if (q == 2) { if (u + 2 < NT) { STAGE_B(slot, u + 2, 0);  STAGE_B(slot, u + 2, 1); } }
      else             { if (u + 2 < NT) { STAGE_B(slot, u + 2, 2);  STAGE_B(slot, u + 2, 3); } }
      __builtin_amdgcn_s_barrier();
      asm volatile("s_waitcnt lgkmcnt(0)" ::: "memory");
      __builtin_amdgcn_sched_barrier(0);
      __builtin_amdgcn_s_setprio(1);
#pragma unroll
      for (int d = 0; d < 2; ++d)
#pragma unroll
        for (int j = 0; j < 4; ++j)
#pragma unroll
          for (int ks = 0; ks < 2; ++ks)
            acc[2 * q + d][j] =
                __builtin_amdgcn_mfma_f32_16x16x32_bf16(av[d][ks], bv[j][ks], acc[2 * q + d][j], 0, 0, 0);
      __builtin_amdgcn_s_setprio(0);
      if (q == 3) {
        if (u + 2 < NT) { asm volatile("s_waitcnt vmcnt(4)" ::: "memory"); }
        else            { asm volatile("s_waitcnt vmcnt(0)" ::: "memory"); }
      }
      __builtin_amdgcn_s_barrier();
      __builtin_amdgcn_sched_barrier(0);
    }
  }
#undef STAGE_A
#undef STAGE_B

  // ---- epilogue: C/D layout col = lane&15, row = (lane>>4)*4 + reg ----
  const int wcol0 = bn0 + wn * 64;
  const int rowb = bm0 + wm * 128 + (l >> 4) * 4;

  if (MODE == 0) {
    float* Op = (float*)O0;
    const int colb = wcol0 + (l & 15);
#pragma unroll
    for (int i = 0; i < 8; ++i)
#pragma unroll
      for (int j = 0; j < 4; ++j)
#pragma unroll
        for (int r = 0; r < 4; ++r)
          Op[(long long)(rowb + i * 16 + r) * 1024 + (colb + j * 16)] = acc[i][j][r];
  } else {
    const int sel = wcol0 >> 10;                   // 0:q 1:k 2:v
    const int col_in = wcol0 & 1023;
    const int h = col_in >> 6;
    if (sel < 2) {
#pragma unroll
      for (int i = 0; i < 8; ++i)
#pragma unroll
        for (int r = 0; r < 4; ++r) {
          float s = 0.f;
#pragma unroll
          for (int j = 0; j < 4; ++j) s += acc[i][j][r] * acc[i][j][r];
          s += __shfl_xor(s, 1); s += __shfl_xor(s, 2);
          s += __shfl_xor(s, 4); s += __shfl_xor(s, 8);
          const float inv = 1.f / fmaxf(sqrtf(s), 1e-12f);
#pragma unroll
          for (int j = 0; j < 4; ++j) acc[i][j][r] *= inv;
        }
    } else {
      const float sig = 1.f / (1.f + expf(-nc[h]));
      const float vsc = expf(-6.9314718055994530942f * sig);  // 1024^-sig
#pragma unroll
      for (int i = 0; i < 8; ++i)
#pragma unroll
        for (int j = 0; j < 4; ++j)
#pragma unroll
          for (int r = 0; r < 4; ++r) acc[i][j][r] *= vsc;
    }
    if (sel == 0) {
      unsigned short* Op = (unsigned short*)O0;
      const int colb = col_in + (l & 15);
#pragma unroll
      for (int i = 0; i < 8; ++i)
#pragma unroll
        for (int j = 0; j < 4; ++j)
#pragma unroll
          for (int r = 0; r < 4; ++r)
            Op[(long long)(rowb + i * 16 + r) * 1024 + (colb + j * 16)] = f2bf(acc[i][j][r]);
    } else {
      // layout L per (n,h): elem(d,c) -> (c>>2)*256 + d*4 + (c&3); 65536 elems/(n,h)
      unsigned short* Tp = (unsigned short*)(sel == 1 ? O1 : O2)
                         + (long long)((bm0 >> 10) * 16 + h) * 65536;
      const int cbase = (bm0 & 1023) + wm * 128 + (l >> 4) * 4;   // 4-aligned
#pragma unroll
      for (int j = 0; j < 4; ++j) {
        const int dbase4 = (j * 16 + (l & 15)) * 4;
#pragma unroll
        for (int i = 0; i < 8; ++i) {
          u16x4 o;
#pragma unroll
          for (int r = 0; r < 4; ++r) o[r] = f2bf(acc[i][j][r]);
          *(u16x4*)(Tp + (long long)((cbase >> 2) + i * 4) * 256 + dbase4) = o;
        }
      }
    }
  }
}

// ---------------- kvT[e][d] = sum_c vL(e,c)*kL(d,c) per (n,h), MFMA split-K ----------------
// Inputs in layout L (see above): staging is a flat contiguous 8KB copy per (wave,cc);
// fragment reads are paired ds_read_b64 at +512B. Operand map m=e, n=d (unchanged).
__global__ __launch_bounds__(256) void kv_mfma(
    const unsigned short* __restrict__ vL, const unsigned short* __restrict__ kL,
    unsigned short* __restrict__ kvT)
{
  const int h = blockIdx.x, n = blockIdx.y;
  const int t = threadIdx.x, l = t & 63, w = t >> 6;
  __shared__ char smem[131072];
  const long long base = (long long)(n * 16 + h) * 65536;
  char* wbuf = smem + w * 32768;

#define KV_STAGE(buf_, cc_) do {                                                                  \
    const long long s0 = base + (long long)(w * 64 + (cc_) * 16) * 256;                          \
    _Pragma("unroll")                                                                             \
    for (int i_ = 0; i_ < 8; ++i_) {                                                              \
      __builtin_amdgcn_global_load_lds((gmem_t*)(vL + s0 + i_ * 512 + l * 8),                     \
                                       (lds_t*)((buf_) + i_ * 1024 + l * 16), 16, 0, 0);          \
      __builtin_amdgcn_global_load_lds((gmem_t*)(kL + s0 + i_ * 512 + l * 8),                     \
                                       (lds_t*)((buf_) + 8192 + i_ * 1024 + l * 16), 16, 0, 0);   \
    }                                                                                             \
  } while (0)

  const int chalf = l >> 4;
  f32x4 acc[4][4];
#pragma unroll
  for (int i = 0; i < 4; ++i)
#pragma unroll
    for (int j = 0; j < 4; ++j) acc[i][j] = f32x4{0.f, 0.f, 0.f, 0.f};

  KV_STAGE(wbuf, 0);
  for (int cc = 0; cc < 4; ++cc) {
    char* cur = wbuf + (cc & 1) * 16384;
    if (cc < 3) {
      KV_STAGE(wbuf + ((cc + 1) & 1) * 16384, cc + 1);
      asm volatile("s_waitcnt vmcnt(16)" ::: "memory");
    } else {
      asm volatile("s_waitcnt vmcnt(0)" ::: "memory");
    }
    bf16x8 av[4][2], bvv[4][2];
#pragma unroll
    for (int m = 0; m < 4; ++m)
#pragma unroll
      for (int ks = 0; ks < 2; ++ks) {
        const int a0 = (ks * 4 + chalf) * 1024 + (m * 16 + (l & 15)) * 8;
        av[m][ks]  = ld_pair512(cur + a0);
        bvv[m][ks] = ld_pair512(cur + 8192 + a0);
      }
#pragma unroll
    for (int m = 0; m < 4; ++m)
#pragma unroll
      for (int j = 0; j < 4; ++j)
#pragma unroll
        for (int ks = 0; ks < 2; ++ks)
          acc[m][j] = __builtin_amdgcn_mfma_f32_16x16x32_bf16(av[m][ks], bvv[j][ks], acc[m][j], 0, 0, 0);
  }
#undef KV_STAGE

  __syncthreads();
  float* red = (float*)smem;                        // [4 waves][16 frags][256]
#pragma unroll
  for (int m = 0; m < 4; ++m)
#pragma unroll
    for (int j = 0; j < 4; ++j)
      *(f32x4*)&red[w * 4096 + (m * 4 + j) * 256 + l * 4] = acc[m][j];
  __syncthreads();

  const int e = t >> 2, d0 = (t & 3) * 16;
  const int m = e >> 4, rr = e & 3, lhi = (e & 15) >> 2;
  alignas(16) unsigned short o16[16];
#pragma unroll
  for (int dd = 0; dd < 16; ++dd) {
    const int d = d0 + dd;
    const int f = m * 4 + (d >> 4);
    const int pos = (lhi * 16 + (d & 15)) * 4 + rr;
    float s = red[f * 256 + pos] + red[4096 + f * 256 + pos] +
              red[8192 + f * 256 + pos] + red[12288 + f * 256 + pos];
    o16[dd] = f2bf(s);
  }
  unsigned short* dst = kvT + (long long)(n * 16 + h) * 4096 + e * 64 + d0;
  *(u32x4*)dst = *(const u32x4*)&o16[0];
  *((u32x4*)dst + 1) = *(const u32x4*)&o16[8];
}

// ---------------- attn[c][h*64+e] = sum_d q[c][h*64+d]*kvT[e][d]; in-place over q ----------------
__global__ __launch_bounds__(256) void attn_mfma(
    unsigned short* __restrict__ q, const unsigned short* __restrict__ kvT)
{
  const int ct = blockIdx.x, h = blockIdx.y, n = blockIdx.z;
  const int t = threadIdx.x, l = t & 63, w = t >> 6;
  __shared__ char smem[40960];                     // q tile 32KB + kvT 8KB
  const long long R0 = (long long)n * 1024 + ct * 256;
  {
    const int sr = t >> 3;
    const int sc = (t & 7) ^ (sr & 7);
#pragma unroll
    for (int i = 0; i < 8; ++i) {
      const int r = i * 32 + sr;
      __builtin_amdgcn_global_load_lds((gmem_t*)(q + (R0 + r) * 1024 + h * 64 + sc * 8),
                                       (lds_t*)(smem + r * 128 + (t & 7) * 16), 16, 0, 0);
    }
#pragma unroll
    for (int i = 0; i < 2; ++i) {
      const int r = i * 32 + sr;
      __builtin_amdgcn_global_load_lds((gmem_t*)(kvT + (long long)(n * 16 + h) * 4096 + r * 64 + sc * 8),
                                       (lds_t*)(smem + 32768 + r * 128 + (t & 7) * 16), 16, 0, 0);
    }
  }
  asm volatile("s_waitcnt vmcnt(0)" ::: "memory");
  __syncthreads();

  const int xr = l & 7, chalf = l >> 4;
  f32x4 acc[4][4];
#pragma unroll
  for (int i = 0; i < 4; ++i)
#pragma unroll
    for (int j = 0; j < 4; ++j) acc[i][j] = f32x4{0.f, 0.f, 0.f, 0.f};
  bf16x8 av[4][2], bvv[4][2];
#pragma unroll
  for (int m = 0; m < 4; ++m)
#pragma unroll
    for (int ks = 0; ks < 2; ++ks) {
      const int ch = ((ks * 4 + chalf) ^ xr) * 16;
      av[m][ks]  = *(const bf16x8*)(smem + (w * 64 + m * 16 + (l & 15)) * 128 + ch);
      bvv[m][ks] = *(const bf16x8*)(smem + 32768 + (m * 16 + (l & 15)) * 128 + ch);
    }
#pragma unroll
  for (int m = 0; m < 4; ++m)
#pragma unroll
    for (int j = 0; j < 4; ++j)
#pragma unroll
      for (int ks = 0; ks < 2; ++ks)
        acc[m][j] = __builtin_amdgcn_mfma_f32_16x16x32_bf16(av[m][ks], bvv[j][ks], acc[m][j], 0, 0, 0);

  const int rb = w * 64 + (l >> 4) * 4;
#pragma unroll
  for (int m = 0; m < 4; ++m)
#pragma unroll
    for (int j = 0; j < 4; ++j)
#pragma unroll
      for (int r = 0; r < 4; ++r)
        q[(R0 + rb + m * 16 + r) * 1024 + h * 64 + j * 16 + (l & 15)] = f2bf(acc[m][j][r]);
}

extern "C" void kernel_launch(void* const* d_in, const int* in_sizes, int n_in,
                              void* d_out, int out_size, void* d_ws, size_t ws_size,
                              hipStream_t stream) {
  (void)in_sizes; (void)n_in; (void)out_size; (void)ws_size;
  const float* x  = (const float*)d_in[0];
  const float* Wq = (const float*)d_in[1];
  const float* Wk = (const float*)d_in[2];
  const float* Wv = (const float*)d_in[3];
  const float* Wo = (const float*)d_in[4];
  const float* nc = (const float*)d_in[5];

  // d_out (64 MB fp32) scratch: xb [0,32MB) (dead after QKV), kvT at +32MB (dead before Wo write)
  unsigned short* xb  = (unsigned short*)d_out;
  unsigned short* kvT = (unsigned short*)((char*)d_out + 33554432ll);

  char* ws = (char*)d_ws;
  unsigned short* wqkv = (unsigned short*)ws;          // [3072][1024] = Wq;Wk;Wv
  unsigned short* wob  = wqkv + 3 * 1048576;
  unsigned short* qb   = wob + 1048576;                // q, then attn in place
  unsigned short* kLb  = qb + 16777216;                // k in layout L [n][h][65536]
  unsigned short* vLb  = kLb + 16777216;               // v in layout L [n][h][65536]

  cvt_all<<<10240, 256, 0, stream>>>(x, Wq, Wk, Wv, Wo, xb, wqkv, wob);

  gemm256<12, 1><<<dim3(12, 64), 512, 0, stream>>>(xb, wqkv, qb, kLb, vLb, nc);
  kv_mfma<<<dim3(16, 16), 256, 0, stream>>>(vLb, kLb, kvT);
  attn_mfma<<<dim3(4, 16, 16), 256, 0, stream>>>(qb, kvT);
  gemm256<4, 0><<<dim3(4, 64), 512, 0, stream>>>(qb, wob, d_out, nullptr, nullptr, nullptr);
}